// Round 1
// baseline (213.504 us; speedup 1.0000x reference)
//
#include <hip/hip_runtime.h>
#include <math.h>

// Problem constants (b,c,w,h,z) = (2,64,64,64,64), nz = 32
#define THRESH_SP 1.5f
#define WHZc   262144      // 64*64*64
#define CWHZc  16777216    // 64*WHZc

// workspace layout (floats)
#define WS_PSUM   0        // [2][64] p sums
#define WS_SLOT   128      // [32 slots][2][64][2] {sum,sumsq}
#define WS_SC     8320     // [2][64] BN scale
#define WS_SH     8448     // [2][64] BN shift
#define WS_ZERO_N 8320

__global__ __launch_bounds__(256) void k_zero(float* __restrict__ ws) {
    int i = blockIdx.x * blockDim.x + threadIdx.x;
    if (i < WS_ZERO_N) ws[i] = 0.0f;
}

// p[b][z] = sum over (c,w,h) of x   (mean applied later)
__global__ __launch_bounds__(256) void k_pmean(const float* __restrict__ x,
                                               const float* __restrict__ sp,
                                               float* __restrict__ ws) {
    const int b = blockIdx.x >> 9;           // 512 blocks per sample
    if (sp[b*3 + 2] > THRESH_SP) return;
    const int jb = blockIdx.x & 511;
    __shared__ float s[64];
    const int t = threadIdx.x;
    if (t < 64) s[t] = 0.0f;
    __syncthreads();
    const int idx4 = jb * 256 + t;           // float4 index within sample
    const int z0 = (idx4 & 15) * 4;          // constant per thread (stride % 16 == 0)
    float a0 = 0.f, a1 = 0.f, a2 = 0.f, a3 = 0.f;
    const float* xb = x + (size_t)b * CWHZc;
#pragma unroll 4
    for (int it = 0; it < 32; ++it) {
        const float4 v = *(const float4*)&xb[(size_t)(idx4 + it * 131072) * 4];
        a0 += v.x; a1 += v.y; a2 += v.z; a3 += v.w;
    }
    // lanes {l, l^16, l^32, l^48} share z0 -> reduce first
    a0 += __shfl_xor(a0, 16); a0 += __shfl_xor(a0, 32);
    a1 += __shfl_xor(a1, 16); a1 += __shfl_xor(a1, 32);
    a2 += __shfl_xor(a2, 16); a2 += __shfl_xor(a2, 32);
    a3 += __shfl_xor(a3, 16); a3 += __shfl_xor(a3, 32);
    if ((t & 63) < 16) {
        unsafeAtomicAdd(&s[z0 + 0], a0);
        unsafeAtomicAdd(&s[z0 + 1], a1);
        unsafeAtomicAdd(&s[z0 + 2], a2);
        unsafeAtomicAdd(&s[z0 + 3], a3);
    }
    __syncthreads();
    if (t < 64) unsafeAtomicAdd(&ws[WS_PSUM + b * 64 + t], s[t]);
}

#define FMA16(A, wv, xv)                                                              \
    A[0][0] += wv.x * xv.x; A[0][1] += wv.x * xv.y; A[0][2] += wv.x * xv.z; A[0][3] += wv.x * xv.w; \
    A[1][0] += wv.y * xv.x; A[1][1] += wv.y * xv.y; A[1][2] += wv.y * xv.z; A[1][3] += wv.y * xv.w; \
    A[2][0] += wv.z * xv.x; A[2][1] += wv.z * xv.y; A[2][2] += wv.z * xv.z; A[2][3] += wv.z * xv.w; \
    A[3][0] += wv.w * xv.x; A[3][1] += wv.w * xv.y; A[3][2] += wv.w * xv.z; A[3][3] += wv.w * xv.w;

// one block per (b, wi, hi) column: full fused attention, writes pre-BN wy to out
__global__ __launch_bounds__(256, 3) void k_main(
    const float* __restrict__ x, const float* __restrict__ sp,
    const float* __restrict__ gw, const float* __restrict__ gb,
    const float* __restrict__ pw, const float* __restrict__ pb,
    const float* __restrict__ Wwp, const float* __restrict__ Wbp,
    float* __restrict__ out, float* __restrict__ ws) {
    const int blk = blockIdx.x;
    const int b = blk >> 12;
    if (sp[b*3 + 2] > THRESH_SP) return;   // gated sample: skip entirely
    const int wh = blk & 4095;
    const int wi = wh >> 6, hi = wh & 63;

    __shared__ float x_s[4096];      // x column [c][z]; later y [i][z]
    __shared__ float wbuf[4096];     // gw^T / phiw^T / Ww^T [k][64]; also f [64][33]
    __shared__ float gp_s[64 * 34];  // pooled g [i][n] (pad 34 for 8B align + banks)
    __shared__ float php_s[64 * 34]; // pooled phi [c][n]; later a [n][z] (32*64=2048)
    __shared__ float p_s[64];

    const int t = threadIdx.x;
    const int xbase = b * CWHZc + (wi * 64 + hi) * 64;

    // ---- phase 1: stage x column, gw^T, p ----
    {
        const int i = t & 63, c0 = (t >> 6) << 2;
#pragma unroll
        for (int r = 0; r < 4; ++r) {
            const int cc = c0 + (r << 4);
            const float4 wv = *(const float4*)&gw[i * 64 + cc];
            wbuf[(cc + 0) * 64 + i] = wv.x;
            wbuf[(cc + 1) * 64 + i] = wv.y;
            wbuf[(cc + 2) * 64 + i] = wv.z;
            wbuf[(cc + 3) * 64 + i] = wv.w;
        }
#pragma unroll
        for (int k = 0; k < 4; ++k) {
            const int f = t + (k << 8);
            const int c = f >> 4, zq = f & 15;
            *(float4*)&x_s[c * 64 + zq * 4] = *(const float4*)&x[xbase + c * WHZc + zq * 4];
        }
        if (t < 64) p_s[t] = ws[WS_PSUM + b * 64 + t] * (1.0f / 262144.0f);
    }
    __syncthreads();

    const int tz = t & 15, ti = t >> 4;
    const int z0 = tz << 2, i0 = ti << 2;

    // ---- G: g[i][z] = gb[i] + sum_c gw[i][c]*x[c][z]; maxpool z-pairs -> gp[i][n] ----
    {
        float acc[4][4];
#pragma unroll
        for (int ki = 0; ki < 4; ki++) {
            const float bv = gb[i0 + ki];
#pragma unroll
            for (int kz = 0; kz < 4; kz++) acc[ki][kz] = bv;
        }
#pragma unroll 4
        for (int c = 0; c < 64; c++) {
            const float4 xv = *(const float4*)&x_s[c * 64 + z0];
            const float4 wv = *(const float4*)&wbuf[c * 64 + i0];
            FMA16(acc, wv, xv)
        }
        const int n0 = z0 >> 1;
#pragma unroll
        for (int ki = 0; ki < 4; ki++) {
            gp_s[(i0 + ki) * 34 + n0]     = fmaxf(acc[ki][0], acc[ki][1]);
            gp_s[(i0 + ki) * 34 + n0 + 1] = fmaxf(acc[ki][2], acc[ki][3]);
        }
    }
    __syncthreads();

    // ---- stage phi_w^T into wbuf; x_s <- x*p (xp) in place ----
    {
        const int i = t & 63, c0 = (t >> 6) << 2;
#pragma unroll
        for (int r = 0; r < 4; ++r) {
            const int cc = c0 + (r << 4);
            const float4 wv = *(const float4*)&pw[i * 64 + cc];
            wbuf[(cc + 0) * 64 + i] = wv.x;
            wbuf[(cc + 1) * 64 + i] = wv.y;
            wbuf[(cc + 2) * 64 + i] = wv.z;
            wbuf[(cc + 3) * 64 + i] = wv.w;
        }
#pragma unroll
        for (int k = 0; k < 4; ++k) {
            const int f = t + (k << 8);
            const int c = f >> 4, zq = f & 15;
            float4 v = *(float4*)&x_s[c * 64 + zq * 4];
            const float4 pv = *(const float4*)&p_s[zq * 4];
            v.x *= pv.x; v.y *= pv.y; v.z *= pv.z; v.w *= pv.w;
            *(float4*)&x_s[c * 64 + zq * 4] = v;
        }
    }
    __syncthreads();

    // ---- PHI: phi[i][z] = pb[i] + sum_c pw[i][c]*xp[c][z]; pool -> php[i][n] ----
    {
        float acc[4][4];
#pragma unroll
        for (int ki = 0; ki < 4; ki++) {
            const float bv = pb[i0 + ki];
#pragma unroll
            for (int kz = 0; kz < 4; kz++) acc[ki][kz] = bv;
        }
#pragma unroll 4
        for (int c = 0; c < 64; c++) {
            const float4 xv = *(const float4*)&x_s[c * 64 + z0];
            const float4 wv = *(const float4*)&wbuf[c * 64 + i0];
            FMA16(acc, wv, xv)
        }
        const int n0 = z0 >> 1;
#pragma unroll
        for (int ki = 0; ki < 4; ki++) {
            php_s[(i0 + ki) * 34 + n0]     = fmaxf(acc[ki][0], acc[ki][1]);
            php_s[(i0 + ki) * 34 + n0 + 1] = fmaxf(acc[ki][2], acc[ki][3]);
        }
    }
    __syncthreads();

    // ---- F: f[z][n] = sum_c xp[c][z]*php[c][n] -> wbuf as [64][33] ----
    {
        const int tn = t & 15, tq = t >> 4;
        const int nf0 = tn << 1, zf0 = tq << 2;
        float acc[4][2] = {{0.f,0.f},{0.f,0.f},{0.f,0.f},{0.f,0.f}};
#pragma unroll 4
        for (int c = 0; c < 64; c++) {
            const float4 xv = *(const float4*)&x_s[c * 64 + zf0];
            const float2 pv = *(const float2*)&php_s[c * 34 + nf0];
            acc[0][0] += xv.x * pv.x; acc[0][1] += xv.x * pv.y;
            acc[1][0] += xv.y * pv.x; acc[1][1] += xv.y * pv.y;
            acc[2][0] += xv.z * pv.x; acc[2][1] += xv.z * pv.y;
            acc[3][0] += xv.w * pv.x; acc[3][1] += xv.w * pv.y;
        }
#pragma unroll
        for (int kz = 0; kz < 4; kz++) {
            wbuf[(zf0 + kz) * 33 + nf0]     = acc[kz][0];
            wbuf[(zf0 + kz) * 33 + nf0 + 1] = acc[kz][1];
        }
    }
    __syncthreads();

    // ---- softmax over n per z; a[n][z] -> php_s (aliased) ----
    if (t < 64) {
        float e[32];
        float m = -1e30f;
#pragma unroll
        for (int n = 0; n < 32; n++) { e[n] = wbuf[t * 33 + n]; m = fmaxf(m, e[n]); }
        float ssum = 0.0f;
#pragma unroll
        for (int n = 0; n < 32; n++) { e[n] = __expf(e[n] - m); ssum += e[n]; }
        const float inv = 1.0f / ssum;
#pragma unroll
        for (int n = 0; n < 32; n++) php_s[n * 64 + t] = e[n] * inv;
    }
    __syncthreads();

    // ---- Y: y[i][z] = sum_n gp[i][n]*a[z][n] -> x_s (aliased); stage Ww^T -> wbuf ----
    {
        const int co = t & 63, ii0 = (t >> 6) << 2;
#pragma unroll
        for (int r = 0; r < 4; ++r) {
            const int ii = ii0 + (r << 4);
            const float4 wv = *(const float4*)&Wwp[co * 64 + ii];
            wbuf[(ii + 0) * 64 + co] = wv.x;
            wbuf[(ii + 1) * 64 + co] = wv.y;
            wbuf[(ii + 2) * 64 + co] = wv.z;
            wbuf[(ii + 3) * 64 + co] = wv.w;
        }
        float acc[4][4] = {{0.f,0.f,0.f,0.f},{0.f,0.f,0.f,0.f},{0.f,0.f,0.f,0.f},{0.f,0.f,0.f,0.f}};
#pragma unroll 4
        for (int n = 0; n < 32; n++) {
            const float4 av = *(const float4*)&php_s[n * 64 + z0];
            const float g0 = gp_s[(i0 + 0) * 34 + n];
            const float g1 = gp_s[(i0 + 1) * 34 + n];
            const float g2 = gp_s[(i0 + 2) * 34 + n];
            const float g3 = gp_s[(i0 + 3) * 34 + n];
            acc[0][0] += g0 * av.x; acc[0][1] += g0 * av.y; acc[0][2] += g0 * av.z; acc[0][3] += g0 * av.w;
            acc[1][0] += g1 * av.x; acc[1][1] += g1 * av.y; acc[1][2] += g1 * av.z; acc[1][3] += g1 * av.w;
            acc[2][0] += g2 * av.x; acc[2][1] += g2 * av.y; acc[2][2] += g2 * av.z; acc[2][3] += g2 * av.w;
            acc[3][0] += g3 * av.x; acc[3][1] += g3 * av.y; acc[3][2] += g3 * av.z; acc[3][3] += g3 * av.w;
        }
#pragma unroll
        for (int ki = 0; ki < 4; ki++) {
            float4 v; v.x = acc[ki][0]; v.y = acc[ki][1]; v.z = acc[ki][2]; v.w = acc[ki][3];
            *(float4*)&x_s[(i0 + ki) * 64 + z0] = v;   // y[i][z]; x no longer needed
        }
    }
    __syncthreads();

    // ---- W: wy[co][z] = Wb[co] + sum_i Ww[co][i]*y[i][z]; store + BN stats ----
    {
        float acc[4][4];
#pragma unroll
        for (int ki = 0; ki < 4; ki++) {
            const float bv = Wbp[i0 + ki];
#pragma unroll
            for (int kz = 0; kz < 4; kz++) acc[ki][kz] = bv;
        }
#pragma unroll 4
        for (int i = 0; i < 64; i++) {
            const float4 yv = *(const float4*)&x_s[i * 64 + z0];
            const float4 wv = *(const float4*)&wbuf[i * 64 + i0];
            FMA16(acc, wv, yv)
        }
        const int obase = b * CWHZc + (wi * 64 + hi) * 64;
#pragma unroll
        for (int ki = 0; ki < 4; ki++) {
            float4 v; v.x = acc[ki][0]; v.y = acc[ki][1]; v.z = acc[ki][2]; v.w = acc[ki][3];
            *(float4*)&out[obase + (i0 + ki) * WHZc + z0] = v;
        }
        const int slot = blk & 31;
#pragma unroll
        for (int ki = 0; ki < 4; ki++) {
            float s1 = acc[ki][0] + acc[ki][1] + acc[ki][2] + acc[ki][3];
            float s2 = acc[ki][0]*acc[ki][0] + acc[ki][1]*acc[ki][1] +
                       acc[ki][2]*acc[ki][2] + acc[ki][3]*acc[ki][3];
#pragma unroll
            for (int mk = 8; mk >= 1; mk >>= 1) {
                s1 += __shfl_xor(s1, mk);
                s2 += __shfl_xor(s2, mk);
            }
            if (tz == 0) {
                const int base = WS_SLOT + ((slot * 2 + b) * 64 + (i0 + ki)) * 2;
                unsafeAtomicAdd(&ws[base + 0], s1);
                unsafeAtomicAdd(&ws[base + 1], s2);
            }
        }
    }
}

// BN finalize: scale/shift per (b,c)
__global__ __launch_bounds__(128) void k_stats(const float* __restrict__ gamma,
                                               const float* __restrict__ beta,
                                               float* __restrict__ ws) {
    const int t = threadIdx.x;
    if (t >= 128) return;
    const int b = t >> 6, c = t & 63;
    float S1 = 0.f, S2 = 0.f;
    for (int s = 0; s < 32; s++) {
        S1 += ws[WS_SLOT + ((s * 2 + b) * 64 + c) * 2 + 0];
        S2 += ws[WS_SLOT + ((s * 2 + b) * 64 + c) * 2 + 1];
    }
    const float N = 262144.0f;
    const float mu = S1 / N;
    const float var = fmaxf(S2 / N - mu * mu, 0.0f);
    const float sc = gamma[c] * rsqrtf(var + 1e-5f);
    ws[WS_SC + t] = sc;
    ws[WS_SH + t] = beta[c] - mu * sc;
}

// out = gate ? wy*sc + sh + x : x
__global__ __launch_bounds__(256) void k_final(const float* __restrict__ x,
                                               const float* __restrict__ sp,
                                               float* __restrict__ out,
                                               const float* __restrict__ ws) {
    const bool use0 = sp[2] <= THRESH_SP;
    const bool use1 = sp[5] <= THRESH_SP;
    const int nf4 = (2 * CWHZc) / 4;
    for (int i4 = blockIdx.x * blockDim.x + threadIdx.x; i4 < nf4;
         i4 += gridDim.x * blockDim.x) {
        const int idx = i4 * 4;
        const int b = idx >> 24;
        const bool use = b ? use1 : use0;
        const float4 xv = *(const float4*)&x[idx];
        float4 ov;
        if (use) {
            const int c = (idx >> 18) & 63;
            const float scv = ws[WS_SC + b * 64 + c];
            const float shv = ws[WS_SH + b * 64 + c];
            const float4 wy = *(const float4*)&out[idx];
            ov.x = wy.x * scv + shv + xv.x;
            ov.y = wy.y * scv + shv + xv.y;
            ov.z = wy.z * scv + shv + xv.z;
            ov.w = wy.w * scv + shv + xv.w;
        } else {
            ov = xv;
        }
        *(float4*)&out[idx] = ov;
    }
}

extern "C" void kernel_launch(void* const* d_in, const int* in_sizes, int n_in,
                              void* d_out, int out_size, void* d_ws, size_t ws_size,
                              hipStream_t stream) {
    const float* x     = (const float*)d_in[0];
    const float* spv   = (const float*)d_in[1];
    const float* gw    = (const float*)d_in[2];
    const float* gb    = (const float*)d_in[3];
    const float* pw    = (const float*)d_in[4];
    const float* pb    = (const float*)d_in[5];
    const float* Ww    = (const float*)d_in[6];
    const float* Wb    = (const float*)d_in[7];
    const float* gamma = (const float*)d_in[8];
    const float* beta  = (const float*)d_in[9];
    float* out = (float*)d_out;
    float* ws  = (float*)d_ws;

    k_zero<<<(WS_ZERO_N + 255) / 256, 256, 0, stream>>>(ws);
    k_pmean<<<1024, 256, 0, stream>>>(x, spv, ws);
    k_main<<<8192, 256, 0, stream>>>(x, spv, gw, gb, pw, pb, Ww, Wb, out, ws);
    k_stats<<<1, 128, 0, stream>>>(gamma, beta, ws);
    k_final<<<2048, 256, 0, stream>>>(x, spv, out, ws);
}

// Round 2
// 136.392 us; speedup vs baseline: 1.5654x; 1.5654x over previous
//
#include <hip/hip_runtime.h>
#include <math.h>

// Problem constants (b,c,w,h,z) = (2,64,64,64,64), nz = 32
#define THRESH_SP 1.5f
#define WHZc   262144      // 64*64*64
#define CWHZc  16777216    // 64*WHZc

// workspace layout (floats)
#define WS_PSUM   0        // [2][64] p sums
#define WS_SLOT   128      // [32 slots][2][64][2] {sum,sumsq}
#define WS_SC     8320     // [2][64] BN scale
#define WS_SH     8448     // [2][64] BN shift
#define WS_ZERO_N 8320

typedef __attribute__((ext_vector_type(8))) short bf16x8;
typedef __attribute__((ext_vector_type(4))) float floatx4;

#define MFMA(a, b, c) __builtin_amdgcn_mfma_f32_16x16x32_bf16((a), (b), (c), 0, 0, 0)

__device__ __forceinline__ unsigned short f2b(float f) {
    unsigned int u = __builtin_bit_cast(unsigned int, f);
    return (unsigned short)((u + 0x7FFFu + ((u >> 16) & 1u)) >> 16);  // RNE
}
__device__ __forceinline__ float b2f(unsigned short h) {
    unsigned int u = ((unsigned int)h) << 16;
    return __builtin_bit_cast(float, u);
}
__device__ __forceinline__ unsigned int scale2(unsigned int u, float pv) {
    unsigned short lo = f2b(b2f((unsigned short)(u & 0xffffu)) * pv);
    unsigned short hi = f2b(b2f((unsigned short)(u >> 16)) * pv);
    return (unsigned int)lo | ((unsigned int)hi << 16);
}
__device__ __forceinline__ bf16x8 ldfrag(const unsigned short* p, int elem_off) {
    return *(const bf16x8*)(p + elem_off);
}

__global__ __launch_bounds__(256) void k_zero(float* __restrict__ ws) {
    int i = blockIdx.x * blockDim.x + threadIdx.x;
    if (i < WS_ZERO_N) ws[i] = 0.0f;
}

// p[b][z] = sum over (c,w,h) of x   (mean applied later)
__global__ __launch_bounds__(256) void k_pmean(const float* __restrict__ x,
                                               const float* __restrict__ sp,
                                               float* __restrict__ ws) {
    const int b = blockIdx.x >> 9;           // 512 blocks per sample
    if (sp[b*3 + 2] > THRESH_SP) return;
    const int jb = blockIdx.x & 511;
    __shared__ float s[64];
    const int t = threadIdx.x;
    if (t < 64) s[t] = 0.0f;
    __syncthreads();
    const int idx4 = jb * 256 + t;           // float4 index within sample
    const int z0 = (idx4 & 15) * 4;          // constant per thread
    float a0 = 0.f, a1 = 0.f, a2 = 0.f, a3 = 0.f;
    const float* xb = x + (size_t)b * CWHZc;
#pragma unroll 4
    for (int it = 0; it < 32; ++it) {
        const float4 v = *(const float4*)&xb[(size_t)(idx4 + it * 131072) * 4];
        a0 += v.x; a1 += v.y; a2 += v.z; a3 += v.w;
    }
    a0 += __shfl_xor(a0, 16); a0 += __shfl_xor(a0, 32);
    a1 += __shfl_xor(a1, 16); a1 += __shfl_xor(a1, 32);
    a2 += __shfl_xor(a2, 16); a2 += __shfl_xor(a2, 32);
    a3 += __shfl_xor(a3, 16); a3 += __shfl_xor(a3, 32);
    if ((t & 63) < 16) {
        unsafeAtomicAdd(&s[z0 + 0], a0);
        unsafeAtomicAdd(&s[z0 + 1], a1);
        unsafeAtomicAdd(&s[z0 + 2], a2);
        unsafeAtomicAdd(&s[z0 + 3], a3);
    }
    __syncthreads();
    if (t < 64) unsafeAtomicAdd(&ws[WS_PSUM + b * 64 + t], s[t]);
}

// One block per (b, wi, hi): fully-fused MFMA attention column.
// All LDS matrices are K-contiguous: A as [m][k], B as B^T = [n][k], pad 72 (K=64) / 40 (K=32).
__global__ __launch_bounds__(256, 4) void k_main(
    const float* __restrict__ x, const float* __restrict__ sp,
    const float* __restrict__ gw, const float* __restrict__ gb,
    const float* __restrict__ pw, const float* __restrict__ pb,
    const float* __restrict__ Wwp, const float* __restrict__ Wbp,
    float* __restrict__ out, float* __restrict__ ws) {
    const int blk = blockIdx.x;
    const int b = blk >> 12;
    if (sp[b*3 + 2] > THRESH_SP) return;   // gated sample: skip entirely
    const int wh = blk & 4095;
    const int xbase = b * CWHZc + wh * 64;

    __shared__ unsigned short xT[64 * 72];   // x^T[z][c] -> xp^T -> y^T[z][i]   (9216 B)
    __shared__ unsigned short wb[64 * 72];   // gw[i][c] -> pw[i][c] -> Ww[co][i] (9216 B)
    __shared__ unsigned short gpT[64 * 40];  // g pooled  [i][n]                  (5120 B)
    __shared__ unsigned short phpN[32 * 72]; // php^T [n][i]; later stats f32[128](4608 B)
    __shared__ unsigned short aT[64 * 40];   // softmax a [z][n]                  (5120 B)
    __shared__ float p_s[64];

    const int t  = threadIdx.x;
    const int l  = t & 63;
    const int lr = l & 15;      // frag row/col lane index
    const int lq = l >> 4;      // k-group
    const int zt = (t >> 6) << 4;  // wave's 16-row z band

    // ---- stage x^T (bf16, transposed) + gw + p ----
#pragma unroll
    for (int k = 0; k < 4; ++k) {
        const int f = t + (k << 8);
        const int c = f & 63, zq = f >> 6;
        const float4 v = *(const float4*)&x[xbase + c * WHZc + zq * 4];
        xT[(zq*4 + 0)*72 + c] = f2b(v.x);
        xT[(zq*4 + 1)*72 + c] = f2b(v.y);
        xT[(zq*4 + 2)*72 + c] = f2b(v.z);
        xT[(zq*4 + 3)*72 + c] = f2b(v.w);
    }
#pragma unroll
    for (int k = 0; k < 4; ++k) {
        const int f = t + (k << 8);
        const int i = f >> 4, c4 = f & 15;
        const float4 v = *(const float4*)&gw[i*64 + c4*4];
        uint2 pk;
        pk.x = (unsigned int)f2b(v.x) | ((unsigned int)f2b(v.y) << 16);
        pk.y = (unsigned int)f2b(v.z) | ((unsigned int)f2b(v.w) << 16);
        *(uint2*)&wb[i*72 + c4*4] = pk;
    }
    if (t < 64) p_s[t] = ws[WS_PSUM + b*64 + t] * (1.0f / 262144.0f);
    __syncthreads();

    // ---- G: D[z][i] = sum_c xT[z][c]*gw[i][c] (+gb); maxpool z-pairs -> gpT[i][n] ----
    {
        const bf16x8 a0 = ldfrag(xT, (zt + lr)*72 + lq*8);
        const bf16x8 a1 = ldfrag(xT, (zt + lr)*72 + lq*8 + 32);
        const int n0 = (zt >> 1) + lq*2;
#pragma unroll
        for (int ti = 0; ti < 4; ++ti) {
            const int i = ti*16 + lr;
            const float bv = gb[i];
            floatx4 acc = {bv, bv, bv, bv};
            acc = MFMA(a0, ldfrag(wb, i*72 + lq*8), acc);
            acc = MFMA(a1, ldfrag(wb, i*72 + lq*8 + 32), acc);
            unsigned int pk = (unsigned int)f2b(fmaxf(acc[0], acc[1])) |
                              ((unsigned int)f2b(fmaxf(acc[2], acc[3])) << 16);
            *(unsigned int*)&gpT[i*40 + n0] = pk;   // n0 even -> 4B aligned
        }
    }
    __syncthreads();

    // ---- xT <- xp^T (scale rows by p[z]); stage pw ----
    {
        const int r = t & 63, cb = (t >> 6) * 2;
        const float pv = p_s[r];
#pragma unroll
        for (int cc = 0; cc < 2; ++cc) {
            uint4 q = *(uint4*)&xT[r*72 + (cb + cc)*8];
            q.x = scale2(q.x, pv); q.y = scale2(q.y, pv);
            q.z = scale2(q.z, pv); q.w = scale2(q.w, pv);
            *(uint4*)&xT[r*72 + (cb + cc)*8] = q;
        }
#pragma unroll
        for (int k = 0; k < 4; ++k) {
            const int f = t + (k << 8);
            const int i = f >> 4, c4 = f & 15;
            const float4 v = *(const float4*)&pw[i*64 + c4*4];
            uint2 pk;
            pk.x = (unsigned int)f2b(v.x) | ((unsigned int)f2b(v.y) << 16);
            pk.y = (unsigned int)f2b(v.z) | ((unsigned int)f2b(v.w) << 16);
            *(uint2*)&wb[i*72 + c4*4] = pk;
        }
    }
    __syncthreads();

    // ---- PHI: D[z][i] = sum_c xpT[z][c]*pw[i][c] (+pb); pool -> phpN[n][i] ----
    {
        const bf16x8 a0 = ldfrag(xT, (zt + lr)*72 + lq*8);
        const bf16x8 a1 = ldfrag(xT, (zt + lr)*72 + lq*8 + 32);
        const int n0 = (zt >> 1) + lq*2;
#pragma unroll
        for (int ti = 0; ti < 4; ++ti) {
            const int i = ti*16 + lr;
            const float bv = pb[i];
            floatx4 acc = {bv, bv, bv, bv};
            acc = MFMA(a0, ldfrag(wb, i*72 + lq*8), acc);
            acc = MFMA(a1, ldfrag(wb, i*72 + lq*8 + 32), acc);
            phpN[n0*72 + i]       = f2b(fmaxf(acc[0], acc[1]));
            phpN[(n0 + 1)*72 + i] = f2b(fmaxf(acc[2], acc[3]));
        }
    }
    __syncthreads();

    // ---- F: f[z][n] = sum_i xpT[z][i]*phpN[n][i]; softmax in-register; a -> aT[z][n]; stage Ww ----
    {
        const bf16x8 a0 = ldfrag(xT, (zt + lr)*72 + lq*8);
        const bf16x8 a1 = ldfrag(xT, (zt + lr)*72 + lq*8 + 32);
        floatx4 f0 = {0.f, 0.f, 0.f, 0.f}, f1 = {0.f, 0.f, 0.f, 0.f};
        f0 = MFMA(a0, ldfrag(phpN, lr*72 + lq*8), f0);
        f0 = MFMA(a1, ldfrag(phpN, lr*72 + lq*8 + 32), f0);
        f1 = MFMA(a0, ldfrag(phpN, (16 + lr)*72 + lq*8), f1);
        f1 = MFMA(a1, ldfrag(phpN, (16 + lr)*72 + lq*8 + 32), f1);
#pragma unroll
        for (int r = 0; r < 4; ++r) {
            float m = fmaxf(f0[r], f1[r]);
            m = fmaxf(m, __shfl_xor(m, 1)); m = fmaxf(m, __shfl_xor(m, 2));
            m = fmaxf(m, __shfl_xor(m, 4)); m = fmaxf(m, __shfl_xor(m, 8));
            const float e0 = __expf(f0[r] - m), e1 = __expf(f1[r] - m);
            float s = e0 + e1;
            s += __shfl_xor(s, 1); s += __shfl_xor(s, 2);
            s += __shfl_xor(s, 4); s += __shfl_xor(s, 8);
            const float inv = 1.0f / s;
            const int z = zt + lq*4 + r;
            aT[z*40 + lr]      = f2b(e0 * inv);
            aT[z*40 + lr + 16] = f2b(e1 * inv);
        }
#pragma unroll
        for (int k = 0; k < 4; ++k) {
            const int f = t + (k << 8);
            const int i = f >> 4, c4 = f & 15;
            const float4 v = *(const float4*)&Wwp[i*64 + c4*4];
            uint2 pk;
            pk.x = (unsigned int)f2b(v.x) | ((unsigned int)f2b(v.y) << 16);
            pk.y = (unsigned int)f2b(v.z) | ((unsigned int)f2b(v.w) << 16);
            *(uint2*)&wb[i*72 + c4*4] = pk;
        }
    }
    __syncthreads();

    // ---- Y: y[z][i] = sum_n a[z][n]*gpT[i][n] -> y^T into xT buffer; zero stats ----
    {
        float* statsf = (float*)phpN;
        if (t < 128) statsf[t] = 0.0f;
        const bf16x8 av = ldfrag(aT, (zt + lr)*40 + lq*8);
#pragma unroll
        for (int ti = 0; ti < 4; ++ti) {
            floatx4 acc = {0.f, 0.f, 0.f, 0.f};
            acc = MFMA(av, ldfrag(gpT, (ti*16 + lr)*40 + lq*8), acc);
#pragma unroll
            for (int r = 0; r < 4; ++r)
                xT[(zt + lq*4 + r)*72 + ti*16 + lr] = f2b(acc[r]);
        }
    }
    __syncthreads();

    // ---- W: wy^T[z][co] = sum_i yT[z][i]*Ww[co][i] (+Wb); store + BN stats ----
    {
        float* statsf = (float*)phpN;
        const bf16x8 a0 = ldfrag(xT, (zt + lr)*72 + lq*8);
        const bf16x8 a1 = ldfrag(xT, (zt + lr)*72 + lq*8 + 32);
#pragma unroll
        for (int ti = 0; ti < 4; ++ti) {
            const int co = ti*16 + lr;
            const float bv = Wbp[co];
            floatx4 acc = {bv, bv, bv, bv};
            acc = MFMA(a0, ldfrag(wb, co*72 + lq*8), acc);
            acc = MFMA(a1, ldfrag(wb, co*72 + lq*8 + 32), acc);
            *(float4*)&out[xbase + co * WHZc + zt + lq*4] = *(float4*)&acc;
            float s1 = acc[0] + acc[1] + acc[2] + acc[3];
            float s2 = acc[0]*acc[0] + acc[1]*acc[1] + acc[2]*acc[2] + acc[3]*acc[3];
            s1 += __shfl_xor(s1, 16); s1 += __shfl_xor(s1, 32);
            s2 += __shfl_xor(s2, 16); s2 += __shfl_xor(s2, 32);
            if (lq == 0) {
                atomicAdd(&statsf[co*2],     s1);
                atomicAdd(&statsf[co*2 + 1], s2);
            }
        }
    }
    __syncthreads();
    {
        const float* statsf = (const float*)phpN;
        if (t < 128) {
            const int slot = blk & 31;
            unsafeAtomicAdd(&ws[WS_SLOT + (slot*2 + b)*128 + t], statsf[t]);
        }
    }
}

// BN finalize: scale/shift per (b,c)
__global__ __launch_bounds__(128) void k_stats(const float* __restrict__ gamma,
                                               const float* __restrict__ beta,
                                               float* __restrict__ ws) {
    const int t = threadIdx.x;
    if (t >= 128) return;
    const int b = t >> 6, c = t & 63;
    float S1 = 0.f, S2 = 0.f;
    for (int s = 0; s < 32; s++) {
        S1 += ws[WS_SLOT + ((s * 2 + b) * 64 + c) * 2 + 0];
        S2 += ws[WS_SLOT + ((s * 2 + b) * 64 + c) * 2 + 1];
    }
    const float N = 262144.0f;
    const float mu = S1 / N;
    const float var = fmaxf(S2 / N - mu * mu, 0.0f);
    const float sc = gamma[c] * rsqrtf(var + 1e-5f);
    ws[WS_SC + t] = sc;
    ws[WS_SH + t] = beta[c] - mu * sc;
}

// out = gate ? wy*sc + sh + x : x
__global__ __launch_bounds__(256) void k_final(const float* __restrict__ x,
                                               const float* __restrict__ sp,
                                               float* __restrict__ out,
                                               const float* __restrict__ ws) {
    const bool use0 = sp[2] <= THRESH_SP;
    const bool use1 = sp[5] <= THRESH_SP;
    const int nf4 = (2 * CWHZc) / 4;
    for (int i4 = blockIdx.x * blockDim.x + threadIdx.x; i4 < nf4;
         i4 += gridDim.x * blockDim.x) {
        const int idx = i4 * 4;
        const int b = idx >> 24;
        const bool use = b ? use1 : use0;
        const float4 xv = *(const float4*)&x[idx];
        float4 ov;
        if (use) {
            const int c = (idx >> 18) & 63;
            const float scv = ws[WS_SC + b * 64 + c];
            const float shv = ws[WS_SH + b * 64 + c];
            const float4 wy = *(const float4*)&out[idx];
            ov.x = wy.x * scv + shv + xv.x;
            ov.y = wy.y * scv + shv + xv.y;
            ov.z = wy.z * scv + shv + xv.z;
            ov.w = wy.w * scv + shv + xv.w;
        } else {
            ov = xv;
        }
        *(float4*)&out[idx] = ov;
    }
}

extern "C" void kernel_launch(void* const* d_in, const int* in_sizes, int n_in,
                              void* d_out, int out_size, void* d_ws, size_t ws_size,
                              hipStream_t stream) {
    const float* x     = (const float*)d_in[0];
    const float* spv   = (const float*)d_in[1];
    const float* gw    = (const float*)d_in[2];
    const float* gb    = (const float*)d_in[3];
    const float* pw    = (const float*)d_in[4];
    const float* pb    = (const float*)d_in[5];
    const float* Ww    = (const float*)d_in[6];
    const float* Wb    = (const float*)d_in[7];
    const float* gamma = (const float*)d_in[8];
    const float* beta  = (const float*)d_in[9];
    float* out = (float*)d_out;
    float* ws  = (float*)d_ws;

    k_zero<<<(WS_ZERO_N + 255) / 256, 256, 0, stream>>>(ws);
    k_pmean<<<1024, 256, 0, stream>>>(x, spv, ws);
    k_main<<<8192, 256, 0, stream>>>(x, spv, gw, gb, pw, pb, Ww, Wb, out, ws);
    k_stats<<<1, 128, 0, stream>>>(gamma, beta, ws);
    k_final<<<2048, 256, 0, stream>>>(x, spv, out, ws);
}

// Round 3
// 130.554 us; speedup vs baseline: 1.6354x; 1.0447x over previous
//
#include <hip/hip_runtime.h>
#include <math.h>

// Problem constants (b,c,w,h,z) = (2,64,64,64,64), nz = 32
#define THRESH_SP 1.5f
#define WHZc   262144      // 64*64*64
#define CWHZc  16777216    // 64*WHZc

// workspace layout: floats 0..8447 = stats; wy bf16 region at byte 65536
#define WS_PSUM   0        // [2][64] p sums
#define WS_SLOT   128      // [32 slots][2][64*2] {sum,sumsq}
#define WS_ZERO_N 8320
#define WS_WY_BYTE 65536
#define WS_WY_NEED (WS_WY_BYTE + 2u * CWHZc * 2u)   // 67.2 MB

typedef __attribute__((ext_vector_type(8))) short bf16x8;
typedef __attribute__((ext_vector_type(4))) float floatx4;

#define MFMA(a, b, c) __builtin_amdgcn_mfma_f32_16x16x32_bf16((a), (b), (c), 0, 0, 0)

__device__ __forceinline__ unsigned short f2b(float f) {
    unsigned int u = __builtin_bit_cast(unsigned int, f);
    return (unsigned short)((u + 0x7FFFu + ((u >> 16) & 1u)) >> 16);  // RNE
}
__device__ __forceinline__ float b2f(unsigned short h) {
    unsigned int u = ((unsigned int)h) << 16;
    return __builtin_bit_cast(float, u);
}
__device__ __forceinline__ bf16x8 ldfrag(const unsigned short* p, int elem_off) {
    return *(const bf16x8*)(p + elem_off);
}

__global__ __launch_bounds__(256) void k_zero(float* __restrict__ ws) {
    int i = blockIdx.x * blockDim.x + threadIdx.x;
    if (i < WS_ZERO_N) ws[i] = 0.0f;
}

// p[b][z] = sum over (c,w,h) of x (mean applied later)
__global__ __launch_bounds__(256) void k_pmean(const float* __restrict__ x,
                                               const float* __restrict__ sp,
                                               float* __restrict__ ws) {
    const int b = blockIdx.x >> 9;
    if (sp[b*3 + 2] > THRESH_SP) return;
    const int jb = blockIdx.x & 511;
    __shared__ float s[64];
    const int t = threadIdx.x;
    if (t < 64) s[t] = 0.0f;
    __syncthreads();
    const int idx4 = jb * 256 + t;
    const int z0 = (idx4 & 15) * 4;
    float a0 = 0.f, a1 = 0.f, a2 = 0.f, a3 = 0.f;
    const float* xb = x + (size_t)b * CWHZc;
#pragma unroll 4
    for (int it = 0; it < 32; ++it) {
        const float4 v = *(const float4*)&xb[(size_t)(idx4 + it * 131072) * 4];
        a0 += v.x; a1 += v.y; a2 += v.z; a3 += v.w;
    }
    a0 += __shfl_xor(a0, 16); a0 += __shfl_xor(a0, 32);
    a1 += __shfl_xor(a1, 16); a1 += __shfl_xor(a1, 32);
    a2 += __shfl_xor(a2, 16); a2 += __shfl_xor(a2, 32);
    a3 += __shfl_xor(a3, 16); a3 += __shfl_xor(a3, 32);
    if ((t & 63) < 16) {
        unsafeAtomicAdd(&s[z0 + 0], a0);
        unsafeAtomicAdd(&s[z0 + 1], a1);
        unsafeAtomicAdd(&s[z0 + 2], a2);
        unsafeAtomicAdd(&s[z0 + 3], a3);
    }
    __syncthreads();
    if (t < 64) unsafeAtomicAdd(&ws[WS_PSUM + b * 64 + t], s[t]);
}

// One block per (b, wi, hi). p is factored out of xp: it scales MFMA output rows.
// A-fragments of bf16 x^T are loaded once and reused across G / PHI / F.
__global__ __launch_bounds__(256, 4) void k_main(
    const float* __restrict__ x, const float* __restrict__ sp,
    const float* __restrict__ gw, const float* __restrict__ gb,
    const float* __restrict__ pw, const float* __restrict__ pb,
    const float* __restrict__ Wwp, const float* __restrict__ Wbp,
    float* __restrict__ out, unsigned short* __restrict__ wy16, int use16,
    float* __restrict__ ws) {
    const int blk = blockIdx.x;
    const int b = blk >> 12;
    if (sp[b*3 + 2] > THRESH_SP) return;
    const int wh = blk & 4095;
    const int xbase = b * CWHZc + wh * 64;

    __shared__ unsigned short xT[64 * 72];   // x^T[z][c] bf16; later y^T[z][i]
    __shared__ unsigned short wb[64 * 72];   // gw -> pw -> Ww  [row][k] bf16
    __shared__ unsigned short gpT[64 * 40];  // pooled g [i][n]
    __shared__ unsigned short phpN[32 * 72]; // pooled phi^T [n][i]; aliased f32 stats[128]
    __shared__ unsigned short aT[64 * 40];   // softmax a [z][n]
    __shared__ float p_s[64];

    const int t  = threadIdx.x;
    const int l  = t & 63;
    const int lr = l & 15;
    const int lq = l >> 4;
    const int zt = (t >> 6) << 4;

    // ---- stage x^T (bf16 transposed), gw, p ----
#pragma unroll
    for (int k = 0; k < 4; ++k) {
        const int f = t + (k << 8);
        const int c = f & 63, zq = f >> 6;
        const float4 v = *(const float4*)&x[xbase + c * WHZc + zq * 4];
        xT[(zq*4 + 0)*72 + c] = f2b(v.x);
        xT[(zq*4 + 1)*72 + c] = f2b(v.y);
        xT[(zq*4 + 2)*72 + c] = f2b(v.z);
        xT[(zq*4 + 3)*72 + c] = f2b(v.w);
    }
#pragma unroll
    for (int k = 0; k < 4; ++k) {
        const int f = t + (k << 8);
        const int i = f >> 4, c4 = f & 15;
        const float4 v = *(const float4*)&gw[i*64 + c4*4];
        uint2 pk;
        pk.x = (unsigned int)f2b(v.x) | ((unsigned int)f2b(v.y) << 16);
        pk.y = (unsigned int)f2b(v.z) | ((unsigned int)f2b(v.w) << 16);
        *(uint2*)&wb[i*72 + c4*4] = pk;
    }
    if (t < 64) p_s[t] = ws[WS_PSUM + b*64 + t] * (1.0f / 262144.0f);
    __syncthreads();

    // persistent A-fragments of x^T (rows z = zt+lr, k = c)
    const bf16x8 a0 = ldfrag(xT, (zt + lr)*72 + lq*8);
    const bf16x8 a1 = ldfrag(xT, (zt + lr)*72 + lq*8 + 32);
    // p for this lane's D rows (z = zt + lq*4 + r)
    const float pz0 = p_s[zt + lq*4 + 0], pz1 = p_s[zt + lq*4 + 1];
    const float pz2 = p_s[zt + lq*4 + 2], pz3 = p_s[zt + lq*4 + 3];

    // ---- G: D[z][i] = sum_c x[z][c]*gw[i][c] + gb; maxpool z-pairs -> gpT[i][n] ----
    {
        const int n0 = (zt >> 1) + lq*2;
#pragma unroll
        for (int ti = 0; ti < 4; ++ti) {
            const int i = ti*16 + lr;
            const float bv = gb[i];
            floatx4 acc = {bv, bv, bv, bv};
            acc = MFMA(a0, ldfrag(wb, i*72 + lq*8), acc);
            acc = MFMA(a1, ldfrag(wb, i*72 + lq*8 + 32), acc);
            unsigned int pk = (unsigned int)f2b(fmaxf(acc[0], acc[1])) |
                              ((unsigned int)f2b(fmaxf(acc[2], acc[3])) << 16);
            *(unsigned int*)&gpT[i*40 + n0] = pk;
        }
    }
    __syncthreads();

    // ---- restage pw into wb ----
#pragma unroll
    for (int k = 0; k < 4; ++k) {
        const int f = t + (k << 8);
        const int i = f >> 4, c4 = f & 15;
        const float4 v = *(const float4*)&pw[i*64 + c4*4];
        uint2 pk;
        pk.x = (unsigned int)f2b(v.x) | ((unsigned int)f2b(v.y) << 16);
        pk.y = (unsigned int)f2b(v.z) | ((unsigned int)f2b(v.w) << 16);
        *(uint2*)&wb[i*72 + c4*4] = pk;
    }
    __syncthreads();

    // ---- PHI: phi[z][i] = p[z]*(X Wp^T)[z][i] + pb; pool -> phpN[n][i] ----
    {
        const int n0 = (zt >> 1) + lq*2;
#pragma unroll
        for (int ti = 0; ti < 4; ++ti) {
            const int i = ti*16 + lr;
            floatx4 acc = {0.f, 0.f, 0.f, 0.f};
            acc = MFMA(a0, ldfrag(wb, i*72 + lq*8), acc);
            acc = MFMA(a1, ldfrag(wb, i*72 + lq*8 + 32), acc);
            const float bv = pb[i];
            const float v0 = fmaf(acc[0], pz0, bv), v1 = fmaf(acc[1], pz1, bv);
            const float v2 = fmaf(acc[2], pz2, bv), v3 = fmaf(acc[3], pz3, bv);
            phpN[n0*72 + i]       = f2b(fmaxf(v0, v1));
            phpN[(n0 + 1)*72 + i] = f2b(fmaxf(v2, v3));
        }
    }
    __syncthreads();

    // ---- F: f[z][n] = p[z] * sum_k x[z][k]*php[n][k]; softmax; a -> aT; stage Ww ----
    {
        floatx4 f0 = {0.f, 0.f, 0.f, 0.f}, f1 = {0.f, 0.f, 0.f, 0.f};
        f0 = MFMA(a0, ldfrag(phpN, lr*72 + lq*8), f0);
        f0 = MFMA(a1, ldfrag(phpN, lr*72 + lq*8 + 32), f0);
        f1 = MFMA(a0, ldfrag(phpN, (16 + lr)*72 + lq*8), f1);
        f1 = MFMA(a1, ldfrag(phpN, (16 + lr)*72 + lq*8 + 32), f1);
        const float pz[4] = {pz0, pz1, pz2, pz3};
#pragma unroll
        for (int r = 0; r < 4; ++r) {
            const float fr0 = f0[r] * pz[r], fr1 = f1[r] * pz[r];
            float m = fmaxf(fr0, fr1);
            m = fmaxf(m, __shfl_xor(m, 1)); m = fmaxf(m, __shfl_xor(m, 2));
            m = fmaxf(m, __shfl_xor(m, 4)); m = fmaxf(m, __shfl_xor(m, 8));
            const float e0 = __expf(fr0 - m), e1 = __expf(fr1 - m);
            float s = e0 + e1;
            s += __shfl_xor(s, 1); s += __shfl_xor(s, 2);
            s += __shfl_xor(s, 4); s += __shfl_xor(s, 8);
            const float inv = 1.0f / s;
            const int z = zt + lq*4 + r;
            aT[z*40 + lr]      = f2b(e0 * inv);
            aT[z*40 + lr + 16] = f2b(e1 * inv);
        }
#pragma unroll
        for (int k = 0; k < 4; ++k) {
            const int f = t + (k << 8);
            const int i = f >> 4, c4 = f & 15;
            const float4 v = *(const float4*)&Wwp[i*64 + c4*4];
            uint2 pk;
            pk.x = (unsigned int)f2b(v.x) | ((unsigned int)f2b(v.y) << 16);
            pk.y = (unsigned int)f2b(v.z) | ((unsigned int)f2b(v.w) << 16);
            *(uint2*)&wb[i*72 + c4*4] = pk;
        }
    }
    __syncthreads();

    // ---- Y: y[z][i] = sum_n a[z][n]*gp[i][n] -> y^T into xT; zero stats ----
    {
        float* statsf = (float*)phpN;
        if (t < 128) statsf[t] = 0.0f;
        const bf16x8 av = ldfrag(aT, (zt + lr)*40 + lq*8);
#pragma unroll
        for (int ti = 0; ti < 4; ++ti) {
            floatx4 acc = {0.f, 0.f, 0.f, 0.f};
            acc = MFMA(av, ldfrag(gpT, (ti*16 + lr)*40 + lq*8), acc);
#pragma unroll
            for (int r = 0; r < 4; ++r)
                xT[(zt + lq*4 + r)*72 + ti*16 + lr] = f2b(acc[r]);
        }
    }
    __syncthreads();

    // ---- W: wy^T[z][co] = sum_i y[z][i]*Ww[co][i] + Wb; store + BN stats ----
    {
        float* statsf = (float*)phpN;
        const bf16x8 y0 = ldfrag(xT, (zt + lr)*72 + lq*8);
        const bf16x8 y1 = ldfrag(xT, (zt + lr)*72 + lq*8 + 32);
#pragma unroll
        for (int ti = 0; ti < 4; ++ti) {
            const int co = ti*16 + lr;
            const float bv = Wbp[co];
            floatx4 acc = {bv, bv, bv, bv};
            acc = MFMA(y0, ldfrag(wb, co*72 + lq*8), acc);
            acc = MFMA(y1, ldfrag(wb, co*72 + lq*8 + 32), acc);
            if (use16) {
                uint2 pk;
                pk.x = (unsigned int)f2b(acc[0]) | ((unsigned int)f2b(acc[1]) << 16);
                pk.y = (unsigned int)f2b(acc[2]) | ((unsigned int)f2b(acc[3]) << 16);
                *(uint2*)&wy16[(size_t)xbase + co * WHZc + zt + lq*4] = pk;
            } else {
                *(float4*)&out[xbase + co * WHZc + zt + lq*4] = *(float4*)&acc;
            }
            float s1 = acc[0] + acc[1] + acc[2] + acc[3];
            float s2 = acc[0]*acc[0] + acc[1]*acc[1] + acc[2]*acc[2] + acc[3]*acc[3];
            s1 += __shfl_xor(s1, 16); s1 += __shfl_xor(s1, 32);
            s2 += __shfl_xor(s2, 16); s2 += __shfl_xor(s2, 32);
            if (lq == 0) {
                atomicAdd(&statsf[co*2],     s1);
                atomicAdd(&statsf[co*2 + 1], s2);
            }
        }
    }
    __syncthreads();
    {
        const float* statsf = (const float*)phpN;
        if (t < 128) {
            const int slot = blk & 31;
            unsafeAtomicAdd(&ws[WS_SLOT + (slot*2 + b)*128 + t], statsf[t]);
        }
    }
}

// out = gate ? wy*sc + sh + x : x  (BN finalize folded in; per-block stats derive)
__global__ __launch_bounds__(256) void k_final(const float* __restrict__ x,
                                               const float* __restrict__ sp,
                                               const float* __restrict__ gamma,
                                               const float* __restrict__ beta,
                                               float* __restrict__ out,
                                               const unsigned short* __restrict__ wy16,
                                               int use16,
                                               const float* __restrict__ ws) {
    const bool use0 = sp[2] <= THRESH_SP;
    const bool use1 = sp[5] <= THRESH_SP;
    __shared__ float scf[128], shf[128];
    if ((use0 || use1) && threadIdx.x < 128) {
        const int t = threadIdx.x;
        const int b = t >> 6, c = t & 63;
        float S1 = 0.f, S2 = 0.f;
        for (int s = 0; s < 32; s++) {
            S1 += ws[WS_SLOT + (s*2 + b)*128 + c*2 + 0];
            S2 += ws[WS_SLOT + (s*2 + b)*128 + c*2 + 1];
        }
        const float N = 262144.0f;
        const float mu = S1 / N;
        const float var = fmaxf(S2 / N - mu * mu, 0.0f);
        const float sc = gamma[c] * rsqrtf(var + 1e-5f);
        scf[t] = sc;
        shf[t] = beta[c] - mu * sc;
    }
    __syncthreads();
    const int nf4 = (2 * CWHZc) / 4;
    for (int i4 = blockIdx.x * blockDim.x + threadIdx.x; i4 < nf4;
         i4 += gridDim.x * blockDim.x) {
        const int idx = i4 * 4;
        const int b = idx >> 24;
        const bool use = b ? use1 : use0;
        const float4 xv = *(const float4*)&x[idx];
        float4 ov;
        if (use) {
            const int c = (idx >> 18) & 63;
            const float scv = scf[b * 64 + c];
            const float shv = shf[b * 64 + c];
            float w0, w1, w2, w3;
            if (use16) {
                const uint2 q = *(const uint2*)&wy16[idx];
                w0 = b2f((unsigned short)(q.x & 0xffffu));
                w1 = b2f((unsigned short)(q.x >> 16));
                w2 = b2f((unsigned short)(q.y & 0xffffu));
                w3 = b2f((unsigned short)(q.y >> 16));
            } else {
                const float4 wy = *(const float4*)&out[idx];
                w0 = wy.x; w1 = wy.y; w2 = wy.z; w3 = wy.w;
            }
            ov.x = w0 * scv + shv + xv.x;
            ov.y = w1 * scv + shv + xv.y;
            ov.z = w2 * scv + shv + xv.z;
            ov.w = w3 * scv + shv + xv.w;
        } else {
            ov = xv;
        }
        *(float4*)&out[idx] = ov;
    }
}

extern "C" void kernel_launch(void* const* d_in, const int* in_sizes, int n_in,
                              void* d_out, int out_size, void* d_ws, size_t ws_size,
                              hipStream_t stream) {
    const float* x     = (const float*)d_in[0];
    const float* spv   = (const float*)d_in[1];
    const float* gw    = (const float*)d_in[2];
    const float* gb    = (const float*)d_in[3];
    const float* pw    = (const float*)d_in[4];
    const float* pb    = (const float*)d_in[5];
    const float* Ww    = (const float*)d_in[6];
    const float* Wb    = (const float*)d_in[7];
    const float* gamma = (const float*)d_in[8];
    const float* beta  = (const float*)d_in[9];
    float* out = (float*)d_out;
    float* ws  = (float*)d_ws;
    const int use16 = (ws_size >= (size_t)WS_WY_NEED) ? 1 : 0;
    unsigned short* wy16 = (unsigned short*)((char*)d_ws + WS_WY_BYTE);

    k_zero<<<(WS_ZERO_N + 255) / 256, 256, 0, stream>>>(ws);
    k_pmean<<<1024, 256, 0, stream>>>(x, spv, ws);
    k_main<<<8192, 256, 0, stream>>>(x, spv, gw, gb, pw, pb, Ww, Wb,
                                     out, wy16, use16, ws);
    k_final<<<2048, 256, 0, stream>>>(x, spv, gamma, beta, out, wy16, use16, ws);
}